// Round 3
// baseline (3089.660 us; speedup 1.0000x reference)
//
#include <hip/hip_runtime.h>
#include <math.h>

// Problem constants
#define NB   4        // batch
#define NH   16       // heads
#define DHD  64       // head dim
#define SL   2048     // Lq == Lk
#define DM   1024     // model dim
#define TOPK 205      // ceil(2048 * 0.1)

// ws layout (floats):
//  Q head-major [B,H,L,DH]  : 8M   @ 0
//  K head-major             : 8M   @ 8M
//  V head-major (tanh)      : 8M   @ 16M
//  CTX [B,L,D]              : 8M   @ 24M
//  S scores/attn [chunk,L,L]: adaptive @ 32M (sized from ws_size)
#define WS_Q   0
#define WS_K   8388608
#define WS_V   16777216
#define WS_CTX 25165824
#define WS_S   33554432
#define S_PER_BH 4194304   // 2048*2048 floats per (b,h) plane

// ---------------------------------------------------------------------------
// Generic projection GEMM: out = X @ W^T + bias
// X [8192, 1024], W [1024(out), 1024(in)] row-major.
// mode 0: write head-major [B,H,L,DH]; mode 1: same + tanh; mode 2: plain [M,N]
// Tile 64x64, BK=16, 256 threads, 4x4 per thread.
// ---------------------------------------------------------------------------
__global__ __launch_bounds__(256) void gemm_proj(const float* __restrict__ X,
                                                 const float* __restrict__ W,
                                                 const float* __restrict__ bias,
                                                 float* __restrict__ out,
                                                 int mode)
{
    __shared__ __align__(16) float Xs[16][68];
    __shared__ __align__(16) float Ws[16][68];
    const int t  = threadIdx.x;
    const int tx = t & 15, ty = t >> 4;
    const int n0 = blockIdx.x * 64;
    const int m0 = blockIdx.y * 64;
    const int lr = t >> 2;          // tile row 0..63
    const int lk = (t & 3) * 4;     // k quad within BK

    float c[4][4] = {};

    for (int k0 = 0; k0 < DM; k0 += 16) {
        float4 xa = *(const float4*)&X[(size_t)(m0 + lr) * DM + k0 + lk];
        float4 wa = *(const float4*)&W[(size_t)(n0 + lr) * DM + k0 + lk];
        __syncthreads();            // previous iter's readers done
        Xs[lk + 0][lr] = xa.x; Xs[lk + 1][lr] = xa.y;
        Xs[lk + 2][lr] = xa.z; Xs[lk + 3][lr] = xa.w;
        Ws[lk + 0][lr] = wa.x; Ws[lk + 1][lr] = wa.y;
        Ws[lk + 2][lr] = wa.z; Ws[lk + 3][lr] = wa.w;
        __syncthreads();
        #pragma unroll
        for (int kk = 0; kk < 16; ++kk) {
            float4 a4 = *(const float4*)&Xs[kk][ty * 4];
            float4 b4 = *(const float4*)&Ws[kk][tx * 4];
            float a_[4] = {a4.x, a4.y, a4.z, a4.w};
            float b_[4] = {b4.x, b4.y, b4.z, b4.w};
            #pragma unroll
            for (int i = 0; i < 4; ++i)
                #pragma unroll
                for (int j = 0; j < 4; ++j)
                    c[i][j] = fmaf(a_[i], b_[j], c[i][j]);
        }
    }

    float4 bi = *(const float4*)&bias[n0 + tx * 4];
    float bb_[4] = {bi.x, bi.y, bi.z, bi.w};
    #pragma unroll
    for (int i = 0; i < 4; ++i) {
        int m = m0 + ty * 4 + i;
        float r_[4];
        #pragma unroll
        for (int j = 0; j < 4; ++j) {
            float v = c[i][j] + bb_[j];
            if (mode == 1) v = tanhf(v);
            r_[j] = v;
        }
        float4 r4 = make_float4(r_[0], r_[1], r_[2], r_[3]);
        if (mode == 2) {
            *(float4*)&out[(size_t)m * DM + n0 + tx * 4] = r4;
        } else {
            int b = m >> 11, l = m & 2047, hh = n0 >> 6;
            *(float4*)&out[(((size_t)(b * NH + hh)) * SL + l) * DHD + tx * 4] = r4;
        }
    }
}

// ---------------------------------------------------------------------------
// Scores: S[z,q,k] = 0.25 * sum_d Q[bh,q,d]*K[bh,k,d]; masked -> -20000
// bh = bh0 + z (global); S indexed by local z.
// grid (ktile=32, qtile=32, chunk), 256 threads, 64x64 tile, BK = 64.
// mask is int32 (harness converts bool -> int).
// ---------------------------------------------------------------------------
__global__ __launch_bounds__(256) void scores_kernel(const float* __restrict__ Q,
                                                     const float* __restrict__ Kh,
                                                     const int* __restrict__ mask,
                                                     float* __restrict__ S,
                                                     int bh0)
{
    __shared__ __align__(16) float Qs[64][68];   // [d][q]
    __shared__ __align__(16) float Ks[64][68];   // [d][k]
    const int t  = threadIdx.x;
    const int tx = t & 15, ty = t >> 4;
    const int k0 = blockIdx.x * 64;
    const int q0 = blockIdx.y * 64;
    const int z  = blockIdx.z;
    const int bh = bh0 + z;
    const float* Qbase = Q + ((size_t)bh * SL + q0) * DHD;
    const float* Kbase = Kh + ((size_t)bh * SL + k0) * DHD;

    #pragma unroll
    for (int i = 0; i < 4; ++i) {
        int e = t + 256 * i;
        int row = e >> 4;
        int dq  = (e & 15) * 4;
        float4 qa = *(const float4*)&Qbase[row * DHD + dq];
        float4 ka = *(const float4*)&Kbase[row * DHD + dq];
        Qs[dq + 0][row] = qa.x; Qs[dq + 1][row] = qa.y;
        Qs[dq + 2][row] = qa.z; Qs[dq + 3][row] = qa.w;
        Ks[dq + 0][row] = ka.x; Ks[dq + 1][row] = ka.y;
        Ks[dq + 2][row] = ka.z; Ks[dq + 3][row] = ka.w;
    }
    __syncthreads();

    float c[4][4] = {};
    #pragma unroll 8
    for (int d = 0; d < 64; ++d) {
        float4 a4 = *(const float4*)&Qs[d][ty * 4];
        float4 b4 = *(const float4*)&Ks[d][tx * 4];
        float a_[4] = {a4.x, a4.y, a4.z, a4.w};
        float b_[4] = {b4.x, b4.y, b4.z, b4.w};
        #pragma unroll
        for (int i = 0; i < 4; ++i)
            #pragma unroll
            for (int j = 0; j < 4; ++j)
                c[i][j] = fmaf(a_[i], b_[j], c[i][j]);
    }

    const int b = bh >> 4;
    int4 mk = *(const int4*)&mask[(size_t)b * SL + k0 + tx * 4];
    int m_[4] = {mk.x, mk.y, mk.z, mk.w};
    #pragma unroll
    for (int i = 0; i < 4; ++i) {
        int q = q0 + ty * 4 + i;
        float r_[4];
        #pragma unroll
        for (int j = 0; j < 4; ++j)
            r_[j] = m_[j] ? -20000.0f : c[i][j] * 0.25f;
        *(float4*)&S[((size_t)z * SL + q) * SL + k0 + tx * 4] =
            make_float4(r_[0], r_[1], r_[2], r_[3]);
    }
}

// ---------------------------------------------------------------------------
// Softmax + exact top-k threshold mask, in place on S (local rows).
// One row (2048 values) per wave; 4 waves / block. Row cached in 32 VGPRs.
// Threshold = exact 205th-largest attn value via binary search on float bits.
// ---------------------------------------------------------------------------
__global__ __launch_bounds__(256) void softmax_topk(float* __restrict__ S)
{
    const int wave = threadIdx.x >> 6;
    const int lane = threadIdx.x & 63;
    const size_t row = (size_t)blockIdx.x * 4 + wave;
    float4* Sr = (float4*)(S + row * SL);               // 512 float4

    float4 v[8];
    #pragma unroll
    for (int i = 0; i < 8; ++i) v[i] = Sr[lane + 64 * i];

    // row max
    float m = -1e30f;
    #pragma unroll
    for (int i = 0; i < 8; ++i) {
        m = fmaxf(m, fmaxf(fmaxf(v[i].x, v[i].y), fmaxf(v[i].z, v[i].w)));
    }
    #pragma unroll
    for (int o = 32; o > 0; o >>= 1) m = fmaxf(m, __shfl_xor(m, o, 64));

    // exp and sum
    float sum = 0.0f;
    #pragma unroll
    for (int i = 0; i < 8; ++i) {
        v[i].x = __expf(v[i].x - m); v[i].y = __expf(v[i].y - m);
        v[i].z = __expf(v[i].z - m); v[i].w = __expf(v[i].w - m);
        sum += (v[i].x + v[i].y) + (v[i].z + v[i].w);
    }
    #pragma unroll
    for (int o = 32; o > 0; o >>= 1) sum += __shfl_xor(sum, o, 64);
    float inv = 1.0f / sum;
    #pragma unroll
    for (int i = 0; i < 8; ++i) {
        v[i].x *= inv; v[i].y *= inv; v[i].z *= inv; v[i].w *= inv;
    }

    // binary search on bits: largest t with count(attn >= t) >= TOPK.
    // attn >= 0 so uint bit order == float order. attn_max == inv exactly.
    unsigned lo = 0u, hi = __float_as_uint(inv);
    while (lo < hi) {
        unsigned mid = (lo + hi + 1u) >> 1;
        int cnt = 0;
        #pragma unroll
        for (int i = 0; i < 8; ++i) {
            cnt += (__float_as_uint(v[i].x) >= mid);
            cnt += (__float_as_uint(v[i].y) >= mid);
            cnt += (__float_as_uint(v[i].z) >= mid);
            cnt += (__float_as_uint(v[i].w) >= mid);
        }
        #pragma unroll
        for (int o = 32; o > 0; o >>= 1) cnt += __shfl_xor(cnt, o, 64);
        if (cnt >= TOPK) lo = mid; else hi = mid - 1u;
    }

    #pragma unroll
    for (int i = 0; i < 8; ++i) {
        float4 x = v[i];
        x.x = (__float_as_uint(x.x) >= lo) ? x.x : 0.0f;
        x.y = (__float_as_uint(x.y) >= lo) ? x.y : 0.0f;
        x.z = (__float_as_uint(x.z) >= lo) ? x.z : 0.0f;
        x.w = (__float_as_uint(x.w) >= lo) ? x.w : 0.0f;
        Sr[lane + 64 * i] = x;
    }
}

// ---------------------------------------------------------------------------
// CTX[b, q, h*64+d] = (sum_k attn[z,q,k] * V[bh,k,d]) * Q[bh,q,d]
// grid (qtile=32, chunk), 256 threads; k-loop in tiles of 64.
// ---------------------------------------------------------------------------
__global__ __launch_bounds__(256) void av_kernel(const float* __restrict__ S,
                                                 const float* __restrict__ V,
                                                 const float* __restrict__ Q,
                                                 float* __restrict__ CTX,
                                                 int bh0)
{
    __shared__ __align__(16) float As[64][68];   // [k][q]
    __shared__ __align__(16) float Vs[64][68];   // [k][d]
    const int t  = threadIdx.x;
    const int tx = t & 15, ty = t >> 4;
    const int q0 = blockIdx.x * 64;
    const int z  = blockIdx.y;
    const int bh = bh0 + z;
    const int b  = bh >> 4, hh = bh & 15;

    float c[4][4] = {};

    for (int k0 = 0; k0 < SL; k0 += 64) {
        float4 av[4], vv[4];
        #pragma unroll
        for (int i = 0; i < 4; ++i) {
            int e = t + 256 * i;
            int row = e >> 4;
            int kq  = (e & 15) * 4;
            av[i] = *(const float4*)&S[((size_t)z * SL + q0 + row) * SL + k0 + kq];
            vv[i] = *(const float4*)&V[((size_t)bh * SL + k0 + row) * DHD + kq];
        }
        __syncthreads();
        #pragma unroll
        for (int i = 0; i < 4; ++i) {
            int e = t + 256 * i;
            int row = e >> 4;
            int kq  = (e & 15) * 4;
            As[kq + 0][row] = av[i].x; As[kq + 1][row] = av[i].y;
            As[kq + 2][row] = av[i].z; As[kq + 3][row] = av[i].w;
            *(float4*)&Vs[row][kq] = vv[i];
        }
        __syncthreads();
        #pragma unroll 8
        for (int kk = 0; kk < 64; ++kk) {
            float4 a4 = *(const float4*)&As[kk][ty * 4];
            float4 b4 = *(const float4*)&Vs[kk][tx * 4];
            float a_[4] = {a4.x, a4.y, a4.z, a4.w};
            float b_[4] = {b4.x, b4.y, b4.z, b4.w};
            #pragma unroll
            for (int i = 0; i < 4; ++i)
                #pragma unroll
                for (int j = 0; j < 4; ++j)
                    c[i][j] = fmaf(a_[i], b_[j], c[i][j]);
        }
        __syncthreads();
    }

    #pragma unroll
    for (int i = 0; i < 4; ++i) {
        int q = q0 + ty * 4 + i;
        float4 qg = *(const float4*)&Q[((size_t)bh * SL + q) * DHD + tx * 4];
        float4 r = make_float4(c[i][0] * qg.x, c[i][1] * qg.y,
                               c[i][2] * qg.z, c[i][3] * qg.w);
        *(float4*)&CTX[((size_t)b * SL + q) * DM + hh * DHD + tx * 4] = r;
    }
}

// ---------------------------------------------------------------------------
extern "C" void kernel_launch(void* const* d_in, const int* in_sizes, int n_in,
                              void* d_out, int out_size, void* d_ws, size_t ws_size,
                              hipStream_t stream)
{
    const float* q_in = (const float*)d_in[0];
    const float* k_in = (const float*)d_in[1];
    const float* Wq   = (const float*)d_in[2];
    const float* bq   = (const float*)d_in[3];
    const float* Wk   = (const float*)d_in[4];
    const float* bk   = (const float*)d_in[5];
    const float* Wv   = (const float*)d_in[6];
    const float* bv   = (const float*)d_in[7];
    const float* Wo   = (const float*)d_in[8];
    const float* bo   = (const float*)d_in[9];
    const int*   mask = (const int*)d_in[10];   // bool -> int32 per harness
    float* out = (float*)d_out;
    float* ws  = (float*)d_ws;

    float* Qb  = ws + WS_Q;
    float* Kb  = ws + WS_K;
    float* Vb  = ws + WS_V;
    float* CTX = ws + WS_CTX;
    float* S   = ws + WS_S;

    // Adaptive bh-chunking: how many 16.78 MB score planes fit in the
    // workspace after the 128 MB staging region?  Pure function of ws_size
    // -> identical launch sequence every call (graph-capture safe).
    long s_cap_floats = (long)(ws_size / 4) - (long)WS_S;
    int chunk = 64;
    while (chunk > 1 && (long)chunk * (long)S_PER_BH > s_cap_floats) chunk >>= 1;

    dim3 blk(256);
    gemm_proj<<<dim3(16, 128), blk, 0, stream>>>(q_in, Wq, bq, Qb, 0);
    gemm_proj<<<dim3(16, 128), blk, 0, stream>>>(k_in, Wk, bk, Kb, 0);
    gemm_proj<<<dim3(16, 128), blk, 0, stream>>>(k_in, Wv, bv, Vb, 1);

    for (int bh0 = 0; bh0 < NB * NH; bh0 += chunk) {
        scores_kernel<<<dim3(32, 32, chunk), blk, 0, stream>>>(Qb, Kb, mask, S, bh0);
        softmax_topk<<<dim3(chunk * 512), blk, 0, stream>>>(S);
        av_kernel<<<dim3(32, chunk), blk, 0, stream>>>(S, Vb, Qb, CTX, bh0);
    }

    gemm_proj<<<dim3(16, 128), blk, 0, stream>>>(CTX, Wo, bo, out, 2);
}